// Round 1
// baseline (299.151 us; speedup 1.0000x reference)
//
#include <hip/hip_runtime.h>
#include <cstdint>
#include <cstddef>

#define B_  4
#define S_  4096
#define H_  1024
#define NH_ 16
#define HD_ 64
#define M_  (B_*S_)   // 16384 rows

typedef __bf16 bf16x8 __attribute__((ext_vector_type(8)));
typedef float  f32x4  __attribute__((ext_vector_type(4)));

__device__ __forceinline__ unsigned short f2b(float f) {
  union { float f; unsigned u; } v; v.f = f;
  unsigned r = v.u + 0x7FFFu + ((v.u >> 16) & 1u);
  return (unsigned short)(r >> 16);
}
__device__ __forceinline__ float b2f(unsigned short u) {
  union { unsigned u; float f; } v; v.u = ((unsigned)u) << 16;
  return v.f;
}

#define GLD16(g, l) __builtin_amdgcn_global_load_lds( \
    (const __attribute__((address_space(1))) void*)(g), \
    (__attribute__((address_space(3))) void*)(l), 16, 0, 0)

// ---------------------------------------------------------------- casts
__global__ void cast_f32_bf16(const float* __restrict__ src,
                              unsigned short* __restrict__ dst, int n4) {
  int i = blockIdx.x * blockDim.x + threadIdx.x;
  if (i >= n4) return;
  float4 f = reinterpret_cast<const float4*>(src)[i];
  ushort4 o;
  o.x = f2b(f.x); o.y = f2b(f.y); o.z = f2b(f.z); o.w = f2b(f.w);
  reinterpret_cast<ushort4*>(dst)[i] = o;
}

// ---------------------------------------------------------------- m97-style GEMM
// C[M,1024] = A[M,1024] * Bt[1024,1024]^T   (y = x @ W.T, W row-major N x K)
// 128x128 tile, 4 waves (2x2 of 64x64), BK=32, global_load_lds width 16.
template<int ACT, bool OUTBF>
__global__ __launch_bounds__(256, 2) void gemm_bt(
    const unsigned short* __restrict__ A,
    const unsigned short* __restrict__ Bt,
    void* __restrict__ Cv) {
  __shared__ __align__(16) unsigned short As[128 * 32];
  __shared__ __align__(16) unsigned short Bs[128 * 32];

  const int nwg = gridDim.x;            // 1024, divisible by 8
  const int nx  = nwg >> 3;
  const int bid = blockIdx.x;
  const int b2  = (bid & 7) * nx + (bid >> 3);   // bijective XCD swizzle
  const int tileM = (b2 >> 3) << 7;     // N/128 == 8 tiles
  const int tileN = (b2 & 7) << 7;

  const int lane = threadIdx.x & 63;
  const int wv   = threadIdx.x >> 6;
  const int wm   = (wv >> 1) * 64;
  const int wn   = (wv & 1) * 64;
  const int fr   = lane & 15;
  const int fq   = lane >> 4;

  // staging chunks (16B each); 512 chunks per 8KB tile, 2 per wave-lane
  const int c0 = wv * 128 + lane;
  const int c1 = c0 + 64;
  const int r0 = c0 >> 2, k0 = (c0 & 3) * 8;
  const int r1 = c1 >> 2, k1 = (c1 & 3) * 8;

  f32x4 zero = {0.f, 0.f, 0.f, 0.f};
  f32x4 acc[4][4];
#pragma unroll
  for (int i = 0; i < 4; i++)
#pragma unroll
    for (int j = 0; j < 4; j++) acc[i][j] = zero;

  for (int kk = 0; kk < 1024; kk += 32) {
    GLD16(A  + (size_t)(tileM + r0) * 1024 + kk + k0, &As[wv * 1024]);
    GLD16(A  + (size_t)(tileM + r1) * 1024 + kk + k1, &As[wv * 1024 + 512]);
    GLD16(Bt + (size_t)(tileN + r0) * 1024 + kk + k0, &Bs[wv * 1024]);
    GLD16(Bt + (size_t)(tileN + r1) * 1024 + kk + k1, &Bs[wv * 1024 + 512]);
    __syncthreads();

    bf16x8 af[4], bfv[4];
#pragma unroll
    for (int i = 0; i < 4; i++)
      af[i] = *reinterpret_cast<const bf16x8*>(&As[(wm + i * 16 + fr) * 32 + fq * 8]);
#pragma unroll
    for (int j = 0; j < 4; j++)
      bfv[j] = *reinterpret_cast<const bf16x8*>(&Bs[(wn + j * 16 + fr) * 32 + fq * 8]);
#pragma unroll
    for (int i = 0; i < 4; i++)
#pragma unroll
      for (int j = 0; j < 4; j++)
        acc[i][j] = __builtin_amdgcn_mfma_f32_16x16x32_bf16(af[i], bfv[j], acc[i][j], 0, 0, 0);
    __syncthreads();
  }

#pragma unroll
  for (int i = 0; i < 4; i++)
#pragma unroll
    for (int j = 0; j < 4; j++)
#pragma unroll
      for (int r = 0; r < 4; r++) {
        int row = tileM + wm + i * 16 + fq * 4 + r;
        int col = tileN + wn + j * 16 + fr;
        float v = acc[i][j][r];
        if (ACT == 1) v = v > 0.f ? v : (expf(v) - 1.f);
        if (OUTBF)
          ((unsigned short*)Cv)[(size_t)row * 1024 + col] = f2b(v);
        else
          ((float*)Cv)[(size_t)row * 1024 + col] = v;
      }
}

// ---------------------------------------------------------------- stage 2: KV partials
// kvp[bh*8+ch][d][e] = sum_{s in chunk} K[b,s,h,d] * V[b,s,h,e]
__global__ __launch_bounds__(256) void kv_partial(
    const unsigned short* __restrict__ Kb,
    const unsigned short* __restrict__ Vb,
    float* __restrict__ kvp) {
  __shared__ __align__(16) unsigned short kt[32 * 64];
  __shared__ __align__(16) unsigned short vt[32 * 64];
  const int bh = blockIdx.x >> 3;
  const int ch = blockIdx.x & 7;
  const int b  = bh >> 4, h = bh & 15;
  const int t  = threadIdx.x;
  const int rr = t >> 3;
  const int cc = (t & 7) * 8;
  const int d0 = (t >> 4) * 4;
  const int e0 = (t & 15) * 4;

  float acc[4][4] = {};
  for (int s0 = ch * 512; s0 < ch * 512 + 512; s0 += 32) {
    size_t g = (size_t)(b * S_ + s0 + rr) * H_ + h * 64 + cc;
    *reinterpret_cast<uint4*>(&kt[rr * 64 + cc]) = *reinterpret_cast<const uint4*>(Kb + g);
    *reinterpret_cast<uint4*>(&vt[rr * 64 + cc]) = *reinterpret_cast<const uint4*>(Vb + g);
    __syncthreads();
#pragma unroll 4
    for (int ss = 0; ss < 32; ss++) {
      ushort4 k4 = *reinterpret_cast<const ushort4*>(&kt[ss * 64 + d0]);
      ushort4 v4 = *reinterpret_cast<const ushort4*>(&vt[ss * 64 + e0]);
      float kf[4] = {b2f(k4.x), b2f(k4.y), b2f(k4.z), b2f(k4.w)};
      float vf[4] = {b2f(v4.x), b2f(v4.y), b2f(v4.z), b2f(v4.w)};
#pragma unroll
      for (int i = 0; i < 4; i++)
#pragma unroll
        for (int j = 0; j < 4; j++) acc[i][j] += kf[i] * vf[j];
    }
    __syncthreads();
  }
  float* outp = kvp + (size_t)blockIdx.x * 4096;
#pragma unroll
  for (int i = 0; i < 4; i++)
#pragma unroll
    for (int j = 0; j < 4; j++) outp[(d0 + i) * 64 + e0 + j] = acc[i][j];
}

// reduce 8 partials, write KV transposed (e-major) in bf16 for stage-3 B-frags
__global__ __launch_bounds__(256) void kv_reduce(
    const float* __restrict__ kvp, unsigned short* __restrict__ KVbT) {
  const int bh = blockIdx.x;
#pragma unroll
  for (int i = 0; i < 16; i++) {
    int idx = threadIdx.x + i * 256;
    float s = 0.f;
#pragma unroll
    for (int ch = 0; ch < 8; ch++) s += kvp[(size_t)(bh * 8 + ch) * 4096 + idx];
    int d = idx >> 6, e = idx & 63;
    KVbT[(size_t)bh * 4096 + e * 64 + d] = f2b(s);
  }
}

// ---------------------------------------------------------------- stage 3: O = Q @ KV per head
// one wave per 64-row tile; frags straight from global (KV is L2-resident)
__global__ __launch_bounds__(64) void qkv_apply(
    const unsigned short* __restrict__ Qb,
    const unsigned short* __restrict__ KVbT,
    unsigned short* __restrict__ Ob) {
  const int blk = blockIdx.x;
  const int mt  = blk & 63;
  const int bh  = blk >> 6;
  const int b   = bh >> 4, h = bh & 15;
  const int lane = threadIdx.x;
  const int fr = lane & 15, fq = lane >> 4;
  const size_t rowbase = (size_t)b * S_ + mt * 64;

  f32x4 zero = {0.f, 0.f, 0.f, 0.f};
  f32x4 acc[4][4];
#pragma unroll
  for (int i = 0; i < 4; i++)
#pragma unroll
    for (int j = 0; j < 4; j++) acc[i][j] = zero;

#pragma unroll
  for (int kk = 0; kk < 64; kk += 32) {
    bf16x8 af[4], bfv[4];
#pragma unroll
    for (int i = 0; i < 4; i++)
      af[i] = *reinterpret_cast<const bf16x8*>(
          Qb + (rowbase + i * 16 + fr) * H_ + h * 64 + kk + fq * 8);
#pragma unroll
    for (int j = 0; j < 4; j++)
      bfv[j] = *reinterpret_cast<const bf16x8*>(
          KVbT + (size_t)bh * 4096 + (j * 16 + fr) * 64 + kk + fq * 8);
#pragma unroll
    for (int i = 0; i < 4; i++)
#pragma unroll
      for (int j = 0; j < 4; j++)
        acc[i][j] = __builtin_amdgcn_mfma_f32_16x16x32_bf16(af[i], bfv[j], acc[i][j], 0, 0, 0);
  }

#pragma unroll
  for (int i = 0; i < 4; i++)
#pragma unroll
    for (int j = 0; j < 4; j++)
#pragma unroll
      for (int r = 0; r < 4; r++)
        Ob[(rowbase + i * 16 + fq * 4 + r) * H_ + h * 64 + j * 16 + fr] =
            f2b(acc[i][j][r]);
}

// ---------------------------------------------------------------- launch
extern "C" void kernel_launch(void* const* d_in, const int* in_sizes, int n_in,
                              void* d_out, int out_size, void* d_ws, size_t ws_size,
                              hipStream_t stream) {
  (void)in_sizes; (void)n_in; (void)out_size; (void)ws_size;
  const float* X  = (const float*)d_in[0];
  const float* Wq = (const float*)d_in[1];
  const float* Wk = (const float*)d_in[2];
  const float* Wv = (const float*)d_in[3];
  const float* Wo = (const float*)d_in[4];

  char*  ws  = (char*)d_ws;
  size_t off = 0;
  auto alloc = [&](size_t bytes) -> char* {
    char* p = ws + off;
    off += (bytes + 255) & ~(size_t)255;
    return p;
  };
  unsigned short* Xb   = (unsigned short*)alloc((size_t)M_ * H_ * 2);
  unsigned short* Wqb  = (unsigned short*)alloc((size_t)H_ * H_ * 2);
  unsigned short* Wkb  = (unsigned short*)alloc((size_t)H_ * H_ * 2);
  unsigned short* Wvb  = (unsigned short*)alloc((size_t)H_ * H_ * 2);
  unsigned short* Wob  = (unsigned short*)alloc((size_t)H_ * H_ * 2);
  unsigned short* Qb   = (unsigned short*)alloc((size_t)M_ * H_ * 2);
  unsigned short* Kb   = (unsigned short*)alloc((size_t)M_ * H_ * 2);
  unsigned short* Vb   = (unsigned short*)alloc((size_t)M_ * H_ * 2);
  float*          kvp  = (float*)alloc((size_t)64 * 8 * 4096 * 4);
  unsigned short* KVbT = (unsigned short*)alloc((size_t)64 * 4096 * 2);
  unsigned short* Ob   = Xb;  // X no longer needed after stage-1 GEMMs

  cast_f32_bf16<<<(M_ * H_) / 1024, 256, 0, stream>>>(X, Xb, (M_ * H_) / 4);
  cast_f32_bf16<<<(H_ * H_) / 1024, 256, 0, stream>>>(Wq, Wqb, (H_ * H_) / 4);
  cast_f32_bf16<<<(H_ * H_) / 1024, 256, 0, stream>>>(Wk, Wkb, (H_ * H_) / 4);
  cast_f32_bf16<<<(H_ * H_) / 1024, 256, 0, stream>>>(Wv, Wvb, (H_ * H_) / 4);
  cast_f32_bf16<<<(H_ * H_) / 1024, 256, 0, stream>>>(Wo, Wob, (H_ * H_) / 4);

  gemm_bt<1, true><<<1024, 256, 0, stream>>>(Xb, Wqb, Qb);   // Q = elu(X Wq^T)
  gemm_bt<1, true><<<1024, 256, 0, stream>>>(Xb, Wkb, Kb);   // K = elu(X Wk^T)
  gemm_bt<0, true><<<1024, 256, 0, stream>>>(Xb, Wvb, Vb);   // V = X Wv^T

  kv_partial<<<512, 256, 0, stream>>>(Kb, Vb, kvp);
  kv_reduce<<<64, 256, 0, stream>>>(kvp, KVbT);
  qkv_apply<<<4096, 64, 0, stream>>>(Qb, KVbT, Ob);

  gemm_bt<0, false><<<1024, 256, 0, stream>>>(Ob, Wob, (float*)d_out);
}

// Round 2
// 258.105 us; speedup vs baseline: 1.1590x; 1.1590x over previous
//
#include <hip/hip_runtime.h>
#include <cstdint>
#include <cstddef>

#define B_  4
#define S_  4096
#define H_  1024
#define NH_ 16
#define M_  (B_*S_)   // 16384 rows

typedef __bf16 bf16x8 __attribute__((ext_vector_type(8)));
typedef float  f32x4  __attribute__((ext_vector_type(4)));

__device__ __forceinline__ unsigned short f2b(float f) {
  union { float f; unsigned u; } v; v.f = f;
  unsigned r = v.u + 0x7FFFu + ((v.u >> 16) & 1u);
  return (unsigned short)(r >> 16);
}
__device__ __forceinline__ float b2f(unsigned short u) {
  union { unsigned u; float f; } v; v.u = ((unsigned)u) << 16;
  return v.f;
}

#define GLD16(g, l) __builtin_amdgcn_global_load_lds( \
    (const __attribute__((address_space(1))) void*)(g), \
    (__attribute__((address_space(3))) void*)(l), 16, 0, 0)

#define VM(n)  asm volatile("s_waitcnt vmcnt(" #n ")" ::: "memory")
#define BAR()  do { asm volatile("" ::: "memory"); __builtin_amdgcn_s_barrier(); \
                    asm volatile("" ::: "memory"); } while (0)

// ---------------------------------------------------------------- casts
__global__ void cast_f32_bf16(const float* __restrict__ src,
                              unsigned short* __restrict__ dst, int n4) {
  int i = blockIdx.x * blockDim.x + threadIdx.x;
  if (i >= n4) return;
  float4 f = reinterpret_cast<const float4*>(src)[i];
  ushort4 o;
  o.x = f2b(f.x); o.y = f2b(f.y); o.z = f2b(f.z); o.w = f2b(f.w);
  reinterpret_cast<ushort4*>(dst)[i] = o;
}

// 4 weights (1M elems each) -> one concatenated bf16 buffer [4][1024][1024]
__global__ void cast_w4(const float* __restrict__ w0, const float* __restrict__ w1,
                        const float* __restrict__ w2, const float* __restrict__ w3,
                        unsigned short* __restrict__ dst) {
  int i = blockIdx.x * blockDim.x + threadIdx.x;      // float4 index, 1M total
  int w = i >> 18, j = i & 0x3FFFF;
  const float* src = (w == 0) ? w0 : (w == 1) ? w1 : (w == 2) ? w2 : w3;
  float4 f = reinterpret_cast<const float4*>(src)[j];
  ushort4 o;
  o.x = f2b(f.x); o.y = f2b(f.y); o.z = f2b(f.z); o.w = f2b(f.w);
  reinterpret_cast<ushort4*>(dst)[i] = o;
}

// ---------------------------------------------------------------- 256x256 8-phase GEMM
// C[M,N] = A[M,1024] * Bt[N,1024]^T, BK=64, 512 thr = 8 waves (2M x 4N),
// per-wave C = (2x4 frag-rows over 2 mq-halves) x (2x2 frag-cols over 2 nq-halves).
// Phase (mq,nq) touches only A-half mq and B-half nq.
// Stage plan per tile t (into buf^1): p1: A0+B0 (4 loads), p2: B1 (2), p3: A1 (2).
// Waits: p1-end vmcnt(6), p2-end vmcnt(6), p3-end none, p4-end vmcnt(4).
// LDS swizzle: 16B-chunk index ^= (row & 7) (both stage-source and reads).
// MODE 0: N=3072, bf16 out routed to Q/K/V with ELU on Q,K.
// MODE 1: N=1024, Bt is per-batch [4][1024][1024], f32 out.
template<int MODE>
__global__ __launch_bounds__(512, 2) void gemm256(
    const unsigned short* __restrict__ A_,
    const unsigned short* __restrict__ Bt_,
    void* __restrict__ out) {
  __shared__ __align__(16) unsigned short LDS[2][2][16384];  // [dbuf][A|B][256*64]

  const int NTN = (MODE == 0) ? 12 : 4;
  const int nx  = gridDim.x >> 3;
  const int b2  = (blockIdx.x & 7) * nx + (blockIdx.x >> 3);  // XCD swizzle (grid%8==0)
  const int tileM = (b2 / NTN) << 8;
  const int tileN = (b2 % NTN) << 8;

  const unsigned short* Bt_e =
      (MODE == 1) ? (Bt_ + ((size_t)(tileM >> 12) << 20)) : Bt_;

  const int tid  = threadIdx.x;
  const int lane = tid & 63, wv = tid >> 6;
  const int wmi  = wv >> 2;     // 0..1  (A-half owner rows within each mq half)
  const int wni  = wv & 3;      // 0..3
  const int fr   = lane & 15, fq = lane >> 4;

  // staging source (pre-swizzled): instr i in {0,1}: chunk c = i*512 + tid
  const int sr0 = tid >> 3,          sc0 = (tid & 7) ^ (sr0 & 7);
  const int sr1 = (tid + 512) >> 3,  sc1 = (tid & 7) ^ (sr1 & 7);

#define STG(NB, ARR, HM, SRC, RB, TT) do {                                      \
    GLD16((SRC) + (size_t)((RB) + (HM)*128 + sr0) * 1024 + (TT)*64 + sc0*8,     \
          &LDS[NB][ARR][(HM)*8192 + wv*512]);                                   \
    GLD16((SRC) + (size_t)((RB) + (HM)*128 + sr1) * 1024 + (TT)*64 + sc1*8,     \
          &LDS[NB][ARR][(HM)*8192 + 4096 + wv*512]);                            \
  } while (0)

  f32x4 zero = {0.f, 0.f, 0.f, 0.f};
  f32x4 acc[2][2][4][2];
#pragma unroll
  for (int a = 0; a < 2; a++)
#pragma unroll
    for (int b = 0; b < 2; b++)
#pragma unroll
      for (int m = 0; m < 4; m++)
#pragma unroll
        for (int n = 0; n < 2; n++) acc[a][b][m][n] = zero;

#define PHASE(CB, MQ, NQ, ...) do {                                             \
    bf16x8 af[4][2], bv[2][2];                                                  \
    _Pragma("unroll")                                                           \
    for (int m = 0; m < 4; m++) {                                               \
      int r = (MQ)*128 + wmi*64 + m*16 + fr;                                    \
      af[m][0] = *(const bf16x8*)&LDS[CB][0][r*64 + (( fq   ) ^ (r&7))*8];      \
      af[m][1] = *(const bf16x8*)&LDS[CB][0][r*64 + ((4+fq  ) ^ (r&7))*8];      \
    }                                                                           \
    _Pragma("unroll")                                                           \
    for (int n = 0; n < 2; n++) {                                               \
      int r = (NQ)*128 + wni*32 + n*16 + fr;                                    \
      bv[n][0] = *(const bf16x8*)&LDS[CB][1][r*64 + (( fq   ) ^ (r&7))*8];      \
      bv[n][1] = *(const bf16x8*)&LDS[CB][1][r*64 + ((4+fq  ) ^ (r&7))*8];      \
    }                                                                           \
    __VA_ARGS__;                                                                \
    __builtin_amdgcn_s_setprio(1);                                              \
    _Pragma("unroll")                                                           \
    for (int m = 0; m < 4; m++)                                                 \
      _Pragma("unroll")                                                         \
      for (int n = 0; n < 2; n++) {                                             \
        acc[MQ][NQ][m][n] = __builtin_amdgcn_mfma_f32_16x16x32_bf16(            \
            af[m][0], bv[n][0], acc[MQ][NQ][m][n], 0, 0, 0);                    \
        acc[MQ][NQ][m][n] = __builtin_amdgcn_mfma_f32_16x16x32_bf16(            \
            af[m][1], bv[n][1], acc[MQ][NQ][m][n], 0, 0, 0);                    \
      }                                                                         \
    __builtin_amdgcn_s_setprio(0);                                              \
  } while (0)

  // prologue: tile 0 fully into buf 0
  STG(0, 0, 0, A_,   tileM, 0);
  STG(0, 0, 1, A_,   tileM, 0);
  STG(0, 1, 0, Bt_e, tileN, 0);
  STG(0, 1, 1, Bt_e, tileN, 0);
  VM(0);
  BAR();

  int cb = 0;
  for (int t = 0; t < 15; ++t) {
    const int nb = cb ^ 1;
    PHASE(cb, 0, 0, STG(nb, 0, 0, A_, tileM, t + 1);
                    STG(nb, 1, 0, Bt_e, tileN, t + 1));
    VM(6); BAR();
    PHASE(cb, 0, 1, STG(nb, 1, 1, Bt_e, tileN, t + 1));
    VM(6); BAR();
    PHASE(cb, 1, 0, STG(nb, 0, 1, A_, tileM, t + 1));
    BAR();
    PHASE(cb, 1, 1, );
    VM(4); BAR();
    cb = nb;
  }
  // last tile (no staging): certify remaining halves as needed
  PHASE(cb, 0, 0, );
  VM(2); BAR();
  PHASE(cb, 0, 1, );
  VM(0); BAR();
  PHASE(cb, 1, 0, );
  PHASE(cb, 1, 1, );

  // epilogue
#pragma unroll
  for (int mq = 0; mq < 2; mq++)
#pragma unroll
    for (int nq = 0; nq < 2; nq++)
#pragma unroll
      for (int m = 0; m < 4; m++)
#pragma unroll
        for (int n = 0; n < 2; n++)
#pragma unroll
          for (int r = 0; r < 4; r++) {
            int row = tileM + mq * 128 + wmi * 64 + m * 16 + fq * 4 + r;
            int col = tileN + nq * 128 + wni * 32 + n * 16 + fr;
            float v = acc[mq][nq][m][n][r];
            if (MODE == 0) {
              int reg = col >> 10, lc = col & 1023;
              if (reg < 2) v = v > 0.f ? v : (expf(v) - 1.f);   // ELU on Q,K
              ((unsigned short*)out)[(size_t)reg * ((size_t)M_ * H_) +
                                     (size_t)row * H_ + lc] = f2b(v);
            } else {
              ((float*)out)[(size_t)row * H_ + col] = v;
            }
          }
#undef PHASE
#undef STG
}

// ---------------------------------------------------------------- stage 2: KV partials
__global__ __launch_bounds__(256) void kv_partial(
    const unsigned short* __restrict__ Kb,
    const unsigned short* __restrict__ Vb,
    float* __restrict__ kvp) {
  __shared__ __align__(16) unsigned short kt[32 * 64];
  __shared__ __align__(16) unsigned short vt[32 * 64];
  const int bh = blockIdx.x >> 3;
  const int ch = blockIdx.x & 7;
  const int b  = bh >> 4, h = bh & 15;
  const int t  = threadIdx.x;
  const int rr = t >> 3;
  const int cc = (t & 7) * 8;
  const int d0 = (t >> 4) * 4;
  const int e0 = (t & 15) * 4;

  float acc[4][4] = {};
  for (int s0 = ch * 512; s0 < ch * 512 + 512; s0 += 32) {
    size_t g = (size_t)(b * S_ + s0 + rr) * H_ + h * 64 + cc;
    *reinterpret_cast<uint4*>(&kt[rr * 64 + cc]) = *reinterpret_cast<const uint4*>(Kb + g);
    *reinterpret_cast<uint4*>(&vt[rr * 64 + cc]) = *reinterpret_cast<const uint4*>(Vb + g);
    __syncthreads();
#pragma unroll 4
    for (int ss = 0; ss < 32; ss++) {
      ushort4 k4 = *reinterpret_cast<const ushort4*>(&kt[ss * 64 + d0]);
      ushort4 v4 = *reinterpret_cast<const ushort4*>(&vt[ss * 64 + e0]);
      float kf[4] = {b2f(k4.x), b2f(k4.y), b2f(k4.z), b2f(k4.w)};
      float vf[4] = {b2f(v4.x), b2f(v4.y), b2f(v4.z), b2f(v4.w)};
#pragma unroll
      for (int i = 0; i < 4; i++)
#pragma unroll
        for (int j = 0; j < 4; j++) acc[i][j] += kf[i] * vf[j];
    }
    __syncthreads();
  }
  float* outp = kvp + (size_t)blockIdx.x * 4096;
#pragma unroll
  for (int i = 0; i < 4; i++)
#pragma unroll
    for (int j = 0; j < 4; j++) outp[(d0 + i) * 64 + e0 + j] = acc[i][j];
}

// reduce 8 partials -> KV[bh][d][e] bf16 (row-major d)
__global__ __launch_bounds__(256) void kv_reduce(
    const float* __restrict__ kvp, unsigned short* __restrict__ KVb) {
  const int bh = blockIdx.x;
#pragma unroll
  for (int i = 0; i < 16; i++) {
    int idx = threadIdx.x + i * 256;
    float s = 0.f;
#pragma unroll
    for (int ch = 0; ch < 8; ch++) s += kvp[(size_t)(bh * 8 + ch) * 4096 + idx];
    KVb[(size_t)bh * 4096 + idx] = f2b(s);
  }
}

// ---------------------------------------------------------------- merged weight
// MbT[b][n][h*64+d] = sum_e KV[b,h][d][e] * Wo[n][h*64+e]   (Bt layout for final GEMM)
__global__ __launch_bounds__(256) void merge_m(
    const unsigned short* __restrict__ KVb,
    const unsigned short* __restrict__ Wob,
    unsigned short* __restrict__ MbT) {
  const int bh = blockIdx.x >> 2;
  const int nc = blockIdx.x & 3;
  const int b  = bh >> 4, h = bh & 15;
  const int lane = threadIdx.x & 63, wv = threadIdx.x >> 6;
  const int fr = lane & 15, fq = lane >> 4;
  const int ncb = nc * 256 + wv * 64;

  f32x4 zero = {0.f, 0.f, 0.f, 0.f};
  f32x4 acc[4][4];
#pragma unroll
  for (int i = 0; i < 4; i++)
#pragma unroll
    for (int j = 0; j < 4; j++) acc[i][j] = zero;

#pragma unroll
  for (int kk = 0; kk < 2; kk++) {
    bf16x8 af[4], bv[4];
#pragma unroll
    for (int i = 0; i < 4; i++)
      af[i] = *(const bf16x8*)&KVb[(size_t)bh * 4096 + (i * 16 + fr) * 64 + kk * 32 + fq * 8];
#pragma unroll
    for (int j = 0; j < 4; j++)
      bv[j] = *(const bf16x8*)&Wob[(size_t)(ncb + j * 16 + fr) * 1024 + h * 64 + kk * 32 + fq * 8];
#pragma unroll
    for (int i = 0; i < 4; i++)
#pragma unroll
      for (int j = 0; j < 4; j++)
        acc[i][j] = __builtin_amdgcn_mfma_f32_16x16x32_bf16(af[i], bv[j], acc[i][j], 0, 0, 0);
  }
#pragma unroll
  for (int i = 0; i < 4; i++)
#pragma unroll
    for (int j = 0; j < 4; j++)
#pragma unroll
      for (int r = 0; r < 4; r++) {
        int n = ncb + j * 16 + fr;
        int k = h * 64 + i * 16 + fq * 4 + r;
        MbT[((size_t)b << 20) + (size_t)n * 1024 + k] = f2b(acc[i][j][r]);
      }
}

// ---------------------------------------------------------------- launch
extern "C" void kernel_launch(void* const* d_in, const int* in_sizes, int n_in,
                              void* d_out, int out_size, void* d_ws, size_t ws_size,
                              hipStream_t stream) {
  (void)in_sizes; (void)n_in; (void)out_size; (void)ws_size;
  const float* X  = (const float*)d_in[0];
  const float* Wq = (const float*)d_in[1];
  const float* Wk = (const float*)d_in[2];
  const float* Wv = (const float*)d_in[3];
  const float* Wo = (const float*)d_in[4];

  char*  ws  = (char*)d_ws;
  size_t off = 0;
  auto alloc = [&](size_t bytes) -> char* {
    char* p = ws + off;
    off += (bytes + 255) & ~(size_t)255;
    return p;
  };
  unsigned short* Xb   = (unsigned short*)alloc((size_t)M_ * H_ * 2);
  unsigned short* Wcat = (unsigned short*)alloc((size_t)4 * H_ * H_ * 2);  // Wq|Wk|Wv|Wo
  unsigned short* QKVb = (unsigned short*)alloc((size_t)3 * M_ * H_ * 2);  // Q|K|V
  float*          kvp  = (float*)alloc((size_t)64 * 8 * 4096 * 4);
  unsigned short* KVb  = (unsigned short*)alloc((size_t)64 * 4096 * 2);
  unsigned short* MbT  = (unsigned short*)alloc((size_t)4 * H_ * H_ * 2);

  unsigned short* Qb = QKVb;
  unsigned short* Kb = QKVb + (size_t)M_ * H_;
  unsigned short* Vb = QKVb + (size_t)2 * M_ * H_;
  unsigned short* Wob = Wcat + (size_t)3 * H_ * H_;

  cast_f32_bf16<<<(M_ * H_) / 1024, 256, 0, stream>>>(X, Xb, (M_ * H_) / 4);
  cast_w4<<<(4 * H_ * H_) / 1024, 256, 0, stream>>>(Wq, Wk, Wv, Wo, Wcat);

  gemm256<0><<<768, 512, 0, stream>>>(Xb, Wcat, QKVb);   // Q,K,V (ELU on Q,K)

  kv_partial<<<512, 256, 0, stream>>>(Kb, Vb, kvp);
  kv_reduce<<<64, 256, 0, stream>>>(kvp, KVb);
  merge_m<<<256, 256, 0, stream>>>(KVb, Wob, MbT);

  gemm256<1><<<256, 512, 0, stream>>>(Qb, MbT, (float*)d_out);  // Y = Q @ M[b]^T
}